// Round 3
// baseline (1485.393 us; speedup 1.0000x reference)
//
#include <hip/hip_runtime.h>

// GCN: 2x GCNConv(sym-norm, self-loops) + relu, then linear head.
// hsb1[i] = bf16(x@W1)[i] RAW (no dinv); dinv[src] folded into agg1 edge
// weight -> GEMM1 independent of CSR build; scatter and GEMM1 fused in one
// kernel (block-range split; GEMM path = round-1 register version, the
// round-2 LDS staging regressed occupancy and is reverted).
// NO CSR SORT: aggregation streams each 128-node bucket's unsorted pairs
// directly, accumulating into an LDS f32 accumulator [128][64] via
// ds_add_f32 (no return -> no dep chains; zero per-node round padding;
// coalesced pair reads). 8-ch groups XOR-swizzled by loc for ~2-way LDS
// bank conflicts; row stride 68 f32 de-aliases rows.
// k_count replaces the sort kernel: bucket-local degree count -> dinv.
// agg1 epilogue: relu finalize -> v bf16 (swizzled, in-place in acc rows)
// -> 8x MFMA 16x16 tiles of v @ W2 -> hsb2 (dinv[dst] folded).
// agg2 epilogue: relu finalize -> dot with Wc -> out.

#define FIN 128
#define HIDDEN 64
#define NBUCK 782          // ceil(100000/128) buckets of 128 nodes
#define CAP 2432           // slots/bucket; mean 2046, sigma~45 (8.5 sigma headroom)
#define EPB 4096           // edges per scatter block

typedef __attribute__((ext_vector_type(8))) short bf16x8;
typedef __attribute__((ext_vector_type(4))) float f32x4;

__device__ __forceinline__ unsigned f2bf_pair(float a, float b) {
    unsigned ua = __float_as_uint(a);
    unsigned ub = __float_as_uint(b);
    ua = (ua + 0x7FFFu + ((ua >> 16) & 1u)) >> 16;
    ub = (ub + 0x7FFFu + ((ub >> 16) & 1u)) & 0xFFFF0000u;
    return ua | ub;
}
__device__ __forceinline__ unsigned short f2bf1(float a) {
    unsigned u = __float_as_uint(a);
    return (unsigned short)((u + 0x7FFFu + ((u >> 16) & 1u)) >> 16);
}
#define BF_LO(u) __uint_as_float((u) << 16)
#define BF_HI(u) __uint_as_float((u) & 0xFFFF0000u)

// ---- fused: edge scatter (blocks < nsc) + GEMM1 (blocks >= nsc) ----
__global__ __launch_bounds__(256) void k_scatter_mfma1(const int* __restrict__ src,
                                                       const int* __restrict__ dst,
                                                       int* __restrict__ bcursor,
                                                       int* __restrict__ pairs, int e,
                                                       const float4* __restrict__ x4,
                                                       const float* __restrict__ w1,
                                                       uint2* __restrict__ hsb,
                                                       int n, int nsc) {
    __shared__ int sbuf[4352];            // 17408 B: sW (GEMM) / h,base,cur (scatter)
    int tid = threadIdx.x;
    if ((int)blockIdx.x < nsc) {
        int* h      = sbuf;
        int* base_s = sbuf + NBUCK;
        int* cur    = sbuf + 2 * NBUCK;
        int dloc[EPB / 256];
        for (int i = tid; i < NBUCK; i += 256) { h[i] = 0; cur[i] = 0; }
        __syncthreads();
        int start = blockIdx.x * EPB;
#pragma unroll
        for (int i = 0; i < EPB / 256; i++) {
            int idx = start + tid + i * 256;
            int d = (idx < e) ? dst[idx] : -1;
            dloc[i] = d;
            if (d >= 0) atomicAdd(&h[d >> 7], 1);
        }
        __syncthreads();
        for (int i = tid; i < NBUCK; i += 256)
            if (h[i] > 0) base_s[i] = atomicAdd(&bcursor[i], h[i]);
        __syncthreads();
#pragma unroll
        for (int i = 0; i < EPB / 256; i++) {
            int idx = start + tid + i * 256;
            int d = dloc[i];
            if (d >= 0) {
                int b = d >> 7;
                int pos = base_s[b] + atomicAdd(&cur[b], 1);
                if (pos < CAP) pairs[b * CAP + pos] = (src[idx] << 7) | (d & 127);
            }
        }
        return;
    }
    // ---- GEMM1 path: hsb[node][ch] = bf16( sum_k x[node][k] W1[k][ch] ) ----
    unsigned short* sW = (unsigned short*)sbuf;   // W1t bf16 [ch][k], stride 136
#pragma unroll
    for (int i = 0; i < 32; i++) {
        int idx = tid + i * 256;              // 0..8191
        int k = idx >> 6, ch = idx & 63;
        sW[ch * 136 + k] = f2bf1(w1[idx]);
    }
    __syncthreads();
    int lane = tid & 63, wave = tid >> 6;
    int quad = lane >> 4, nl = lane & 15;
    int node = (blockIdx.x - nsc) * 64 + wave * 16 + nl;
    int ic = min(node, n - 1);
    const float4* px = x4 + (size_t)ic * 32 + quad * 2;
    bf16x8 bfr[4];
#pragma unroll
    for (int kc = 0; kc < 4; kc++) {
        float4 p = px[kc * 8];
        float4 q = px[kc * 8 + 1];
        union { unsigned u[4]; bf16x8 v; } t;
        t.u[0] = f2bf_pair(p.x, p.y); t.u[1] = f2bf_pair(p.z, p.w);
        t.u[2] = f2bf_pair(q.x, q.y); t.u[3] = f2bf_pair(q.z, q.w);
        bfr[kc] = t.v;
    }
    const bf16x8* sW8 = (const bf16x8*)sW;
    f32x4 a0 = {0.f, 0.f, 0.f, 0.f}, a1 = a0, a2 = a0, a3 = a0;
#pragma unroll
    for (int kc = 0; kc < 4; kc++) {
        int ko = kc * 4 + quad;
        bf16x8 w0 = sW8[(nl +  0) * 17 + ko];
        bf16x8 w1f = sW8[(nl + 16) * 17 + ko];
        bf16x8 w2f = sW8[(nl + 32) * 17 + ko];
        bf16x8 w3f = sW8[(nl + 48) * 17 + ko];
        a0 = __builtin_amdgcn_mfma_f32_16x16x32_bf16(w0,  bfr[kc], a0, 0, 0, 0);
        a1 = __builtin_amdgcn_mfma_f32_16x16x32_bf16(w1f, bfr[kc], a1, 0, 0, 0);
        a2 = __builtin_amdgcn_mfma_f32_16x16x32_bf16(w2f, bfr[kc], a2, 0, 0, 0);
        a3 = __builtin_amdgcn_mfma_f32_16x16x32_bf16(w3f, bfr[kc], a3, 0, 0, 0);
    }
    if (node < n) {
        uint2* o = hsb + (size_t)node * 16 + quad;
        o[0]  = make_uint2(f2bf_pair(a0.x, a0.y), f2bf_pair(a0.z, a0.w));
        o[4]  = make_uint2(f2bf_pair(a1.x, a1.y), f2bf_pair(a1.z, a1.w));
        o[8]  = make_uint2(f2bf_pair(a2.x, a2.y), f2bf_pair(a2.z, a2.w));
        o[12] = make_uint2(f2bf_pair(a3.x, a3.y), f2bf_pair(a3.z, a3.w));
    }
}

// ---- bucket-local degree count -> dinv (replaces the CSR sort kernel) ----
__global__ __launch_bounds__(256) void k_count(const int* __restrict__ pairs,
                                               const int* __restrict__ bcursor,
                                               float* __restrict__ dinv, int n) {
    __shared__ int cnt[128];
    int tid = threadIdx.x, b = blockIdx.x;
    if (tid < 128) cnt[tid] = 0;
    __syncthreads();
    int c = min(bcursor[b], CAP);
    const int* pb = pairs + b * CAP;
    for (int i = tid; i < c; i += 256) atomicAdd(&cnt[pb[i] & 127], 1);
    __syncthreads();
    int node = (b << 7) + tid;
    if (tid < 128 && node < n) dinv[node] = rsqrtf((float)cnt[tid] + 1.0f);
}

// agg layer1 (LDS f32 atomic accumulate over unsorted bucket pairs) +
// finalize(relu) + W2 GEMM -> hsb2.  Block = 128 dst nodes.
__global__ __launch_bounds__(256) void k_agg1_gemm2(const int* __restrict__ pairs,
                                                    const int* __restrict__ bcursor,
                                                    const uint4* __restrict__ hsb4,  // hsb1
                                                    const float* __restrict__ dinv,
                                                    const float* __restrict__ b1,
                                                    const float* __restrict__ w2,    // [64*64]
                                                    uint2* __restrict__ hsb2, int n) {
    __shared__ float acc[128 * 68];           // 34816 B, row stride 68 f32
    __shared__ unsigned short sW[64 * 72];    // W2t bf16 [ch][k], stride 72
    __shared__ float sB1[64];
    int tid = threadIdx.x, b = blockIdx.x;
    int node0 = b << 7;
#pragma unroll
    for (int i = 0; i < 16; i++) {
        int idx = tid + i * 256;              // 0..4095
        int k = idx >> 6, ch = idx & 63;
        sW[ch * 72 + k] = f2bf1(w2[idx]);
    }
    if (tid < 64) sB1[tid] = b1[tid];
#pragma unroll
    for (int i = 0; i < 34; i++) acc[tid + i * 256] = 0.f;   // 8704 = 34*256 exactly
    __syncthreads();
    int cnt = min(bcursor[b], CAP);
    int wave = tid >> 6, lane = tid & 63;
    int ws = (cnt * wave) >> 2, we = (cnt * (wave + 1)) >> 2;
    int el8 = lane >> 3, cq = lane & 7;
    const int* pb = pairs + b * CAP;
#pragma unroll 2
    for (int base = ws; base < we; base += 8) {
        int e = base + el8;
        int p = pb[min(e, we - 1)];
        int s = p >> 7, loc = p & 127;
        float w = (e < we) ? dinv[s] : 0.f;
        uint4 g = hsb4[(size_t)s * 8 + cq];
        float* ar = acc + loc * 68 + ((cq ^ (loc & 7)) << 3);
        atomicAdd(ar + 0, w * BF_LO(g.x)); atomicAdd(ar + 1, w * BF_HI(g.x));
        atomicAdd(ar + 2, w * BF_LO(g.y)); atomicAdd(ar + 3, w * BF_HI(g.y));
        atomicAdd(ar + 4, w * BF_LO(g.z)); atomicAdd(ar + 5, w * BF_HI(g.z));
        atomicAdd(ar + 6, w * BF_LO(g.w)); atomicAdd(ar + 7, w * BF_HI(g.w));
    }
    __syncthreads();
    // epilogue: v = relu(dinv*acc + dinv^2*h_self + b1), bf16-packed back
    // into acc row start (XOR-swizzled 16B groups).
    int row = tid >> 1, h = tid & 1;
    int node = node0 + row;
    bool valid = node < n;
    float sd = valid ? dinv[node] : 0.f;
    float sq = sd * sd;
    float vv[32];
#pragma unroll
    for (int kk = 0; kk < 4; kk++) {
        int grp = h * 4 + kk;
        const float* pr = acc + row * 68 + ((grp ^ (row & 7)) << 3);
        uint4 gs = valid ? hsb4[(size_t)node * 8 + grp] : make_uint4(0, 0, 0, 0);
        int cb = grp * 8;
        vv[kk*8+0] = fmaxf(sd * pr[0] + sq * BF_LO(gs.x) + sB1[cb+0], 0.f);
        vv[kk*8+1] = fmaxf(sd * pr[1] + sq * BF_HI(gs.x) + sB1[cb+1], 0.f);
        vv[kk*8+2] = fmaxf(sd * pr[2] + sq * BF_LO(gs.y) + sB1[cb+2], 0.f);
        vv[kk*8+3] = fmaxf(sd * pr[3] + sq * BF_HI(gs.y) + sB1[cb+3], 0.f);
        vv[kk*8+4] = fmaxf(sd * pr[4] + sq * BF_LO(gs.z) + sB1[cb+4], 0.f);
        vv[kk*8+5] = fmaxf(sd * pr[5] + sq * BF_HI(gs.z) + sB1[cb+5], 0.f);
        vv[kk*8+6] = fmaxf(sd * pr[6] + sq * BF_LO(gs.w) + sB1[cb+6], 0.f);
        vv[kk*8+7] = fmaxf(sd * pr[7] + sq * BF_HI(gs.w) + sB1[cb+7], 0.f);
    }
    __syncthreads();
#pragma unroll
    for (int kk = 0; kk < 4; kk++) {
        int grp = h * 4 + kk;
        uint4 u;
        u.x = f2bf_pair(vv[kk*8+0], vv[kk*8+1]);
        u.y = f2bf_pair(vv[kk*8+2], vv[kk*8+3]);
        u.z = f2bf_pair(vv[kk*8+4], vv[kk*8+5]);
        u.w = f2bf_pair(vv[kk*8+6], vv[kk*8+7]);
        *(uint4*)((char*)acc + row * 272 + ((grp ^ (row & 7)) << 4)) = u;
    }
    __syncthreads();
    // Phase B: 8 node-tiles of 16; wave w -> tiles 2w, 2w+1; full 64 ch each.
    int quad = lane >> 4, nl = lane & 15;
    const bf16x8* sW8 = (const bf16x8*)sW;
#pragma unroll
    for (int tt = 0; tt < 2; tt++) {
        int loc = (wave * 2 + tt) * 16 + nl;
        f32x4 o0 = {0.f, 0.f, 0.f, 0.f}, o1 = o0, o2 = o0, o3 = o0;
#pragma unroll
        for (int kc = 0; kc < 2; kc++) {
            int grp = kc * 4 + quad;
            bf16x8 bv = *(const bf16x8*)((const char*)acc + loc * 272 + ((grp ^ (loc & 7)) << 4));
            o0 = __builtin_amdgcn_mfma_f32_16x16x32_bf16(sW8[(nl +  0) * 9 + grp], bv, o0, 0, 0, 0);
            o1 = __builtin_amdgcn_mfma_f32_16x16x32_bf16(sW8[(nl + 16) * 9 + grp], bv, o1, 0, 0, 0);
            o2 = __builtin_amdgcn_mfma_f32_16x16x32_bf16(sW8[(nl + 32) * 9 + grp], bv, o2, 0, 0, 0);
            o3 = __builtin_amdgcn_mfma_f32_16x16x32_bf16(sW8[(nl + 48) * 9 + grp], bv, o3, 0, 0, 0);
        }
        int onode = node0 + loc;
        if (onode < n) {
            float s = dinv[onode];
            uint2* o = hsb2 + (size_t)onode * 16 + quad;
            o[0]  = make_uint2(f2bf_pair(o0.x * s, o0.y * s), f2bf_pair(o0.z * s, o0.w * s));
            o[4]  = make_uint2(f2bf_pair(o1.x * s, o1.y * s), f2bf_pair(o1.z * s, o1.w * s));
            o[8]  = make_uint2(f2bf_pair(o2.x * s, o2.y * s), f2bf_pair(o2.z * s, o2.w * s));
            o[12] = make_uint2(f2bf_pair(o3.x * s, o3.y * s), f2bf_pair(o3.z * s, o3.w * s));
        }
    }
}

// agg layer2 (same LDS accumulate, m=1: dinv folded in hsb2) + head.
__global__ __launch_bounds__(256) void k_agg2_head(const int* __restrict__ pairs,
                                                   const int* __restrict__ bcursor,
                                                   const uint4* __restrict__ hsb4,  // hsb2
                                                   const float* __restrict__ dinv,
                                                   const float* __restrict__ b2,
                                                   const float* __restrict__ wc,
                                                   const float* __restrict__ bc,
                                                   float* __restrict__ out, int n) {
    __shared__ float acc[128 * 68];           // 34816 B
    __shared__ float sB2[64], sWc[64];
    int tid = threadIdx.x, b = blockIdx.x;
    int node0 = b << 7;
    if (tid < 64) { sB2[tid] = b2[tid]; sWc[tid] = wc[tid]; }
#pragma unroll
    for (int i = 0; i < 34; i++) acc[tid + i * 256] = 0.f;
    __syncthreads();
    int cnt = min(bcursor[b], CAP);
    int wave = tid >> 6, lane = tid & 63;
    int ws = (cnt * wave) >> 2, we = (cnt * (wave + 1)) >> 2;
    int el8 = lane >> 3, cq = lane & 7;
    const int* pb = pairs + b * CAP;
#pragma unroll 2
    for (int base = ws; base < we; base += 8) {
        int e = base + el8;
        int p = pb[min(e, we - 1)];
        int s = p >> 7, loc = p & 127;
        float w = (e < we) ? 1.f : 0.f;
        uint4 g = hsb4[(size_t)s * 8 + cq];
        float* ar = acc + loc * 68 + ((cq ^ (loc & 7)) << 3);
        atomicAdd(ar + 0, w * BF_LO(g.x)); atomicAdd(ar + 1, w * BF_HI(g.x));
        atomicAdd(ar + 2, w * BF_LO(g.y)); atomicAdd(ar + 3, w * BF_HI(g.y));
        atomicAdd(ar + 4, w * BF_LO(g.z)); atomicAdd(ar + 5, w * BF_HI(g.z));
        atomicAdd(ar + 6, w * BF_LO(g.w)); atomicAdd(ar + 7, w * BF_HI(g.w));
    }
    __syncthreads();
    // epilogue: out[node] = relu(dinv*(acc + self) + b2) . wc + bc
    int row = tid >> 1, h = tid & 1;
    int node = node0 + row;
    if (node >= n) return;
    float sd = dinv[node];
    float t = 0.f;
#pragma unroll
    for (int kk = 0; kk < 4; kk++) {
        int grp = h * 4 + kk;
        const float* pr = acc + row * 68 + ((grp ^ (row & 7)) << 3);
        uint4 gs = hsb4[(size_t)node * 8 + grp];
        int cb = grp * 8;
        t += fmaxf(sd * (pr[0] + BF_LO(gs.x)) + sB2[cb+0], 0.f) * sWc[cb+0]
           + fmaxf(sd * (pr[1] + BF_HI(gs.x)) + sB2[cb+1], 0.f) * sWc[cb+1]
           + fmaxf(sd * (pr[2] + BF_LO(gs.y)) + sB2[cb+2], 0.f) * sWc[cb+2]
           + fmaxf(sd * (pr[3] + BF_HI(gs.y)) + sB2[cb+3], 0.f) * sWc[cb+3]
           + fmaxf(sd * (pr[4] + BF_LO(gs.z)) + sB2[cb+4], 0.f) * sWc[cb+4]
           + fmaxf(sd * (pr[5] + BF_HI(gs.z)) + sB2[cb+5], 0.f) * sWc[cb+5]
           + fmaxf(sd * (pr[6] + BF_LO(gs.w)) + sB2[cb+6], 0.f) * sWc[cb+6]
           + fmaxf(sd * (pr[7] + BF_HI(gs.w)) + sB2[cb+7], 0.f) * sWc[cb+7];
    }
    t += __shfl_xor(t, 1);
    if (h == 0) out[node] = t + bc[0];
}

extern "C" void kernel_launch(void* const* d_in, const int* in_sizes, int n_in,
                              void* d_out, int out_size, void* d_ws, size_t ws_size,
                              hipStream_t stream) {
    const float* x  = (const float*)d_in[0];
    const int*   ei = (const int*)d_in[1];
    const float* W1 = (const float*)d_in[2];
    const float* b1 = (const float*)d_in[3];
    const float* W2 = (const float*)d_in[4];
    const float* b2 = (const float*)d_in[5];
    const float* Wc = (const float*)d_in[6];
    const float* bc = (const float*)d_in[7];
    int n = in_sizes[0] / FIN;      // 100000
    int e = in_sizes[1] / 2;        // 1600000
    const int* srcv = ei;
    const int* dstv = ei + e;

    char* ws = (char*)d_ws;
    float* dinv    = (float*)(ws + 0);                       // 400 KB
    int*   bcursor = (int*)(ws + (512u << 10));              // 3128 B
    int*   pairs   = (int*)(ws + (1u << 20));                // 7.26 MB (782*2432*4) — LIVE through agg2
    uint2* hsb1    = (uint2*)(ws + (9u << 20));              // 12.8 MB bf16 [N,64]
    uint2* hsb2    = (uint2*)(ws + (22u << 20));             // 12.8 MB bf16 [N,64]

    int nb_sc   = (e + EPB - 1) / EPB;   // 391
    int nb_rows = (n + 63) / 64;         // 1563

    hipMemsetAsync(bcursor, 0, NBUCK * sizeof(int), stream);
    // fused: edge-bucket scatter (391 blocks) || layer-1 GEMM (1563 blocks)
    k_scatter_mfma1<<<nb_sc + nb_rows, 256, 0, stream>>>(srcv, dstv, bcursor, pairs, e,
                                                         (const float4*)x, W1, hsb1,
                                                         n, nb_sc);
    // bucket-local degree -> dinv (no sort)
    k_count<<<NBUCK, 256, 0, stream>>>(pairs, bcursor, dinv, n);
    // layer-1 agg (LDS atomic accumulate) + finalize + layer-2 GEMM fused
    k_agg1_gemm2<<<NBUCK, 256, 0, stream>>>(pairs, bcursor, (const uint4*)hsb1,
                                            dinv, b1, W2, hsb2, n);
    // layer-2 agg + head
    k_agg2_head<<<NBUCK, 256, 0, stream>>>(pairs, bcursor, (const uint4*)hsb2,
                                           dinv, b2, Wc, bc, (float*)d_out, n);
}

// Round 4
// 211.143 us; speedup vs baseline: 7.0350x; 7.0350x over previous
//
#include <hip/hip_runtime.h>

// GCN: 2x GCNConv(sym-norm, self-loops) + relu, then linear head.
// Structure = round-1 (best measured 210.9us) + surgical fixes:
//  - k_prep pre-transposes W1/W2 to bf16 [ch][k] in ws (+ zeroes bcursor),
//    so hot-kernel LDS staging is 2-4x dwordx4 + ds_write_b128 per thread
//    instead of ~130 scalar-load/convert/ds_write_b16 instrs per block.
//  - GEMM1: 128 nodes/block (782 blocks) amortizes staging 2x.
//  - agg: 8 lanes/node (32 nodes/block): each lane owns its 8 channels for
//    ALL edges -> register accumulate, NO shuffles, NO LDS atomics
//    (round-3 lesson: LDS atomic streaming = 15x regression).
//    4 independent gathers/lane in flight; round granularity 4.
// dinv[src] folded into agg1 edge weight -> GEMM1 independent of CSR build;
// scatter (391 blocks) || GEMM1 (782 blocks) fused in one dispatch.

#define FIN 128
#define HIDDEN 64
#define NBUCK 391          // ceil(100000/256) buckets of 256 nodes
#define CAP 4608           // slots/bucket; mean 4096, sigma~64
#define EPB 4096           // edges per scatter block

typedef __attribute__((ext_vector_type(8))) short bf16x8;
typedef __attribute__((ext_vector_type(4))) float f32x4;

__device__ __forceinline__ unsigned f2bf_pair(float a, float b) {
    unsigned ua = __float_as_uint(a);
    unsigned ub = __float_as_uint(b);
    ua = (ua + 0x7FFFu + ((ua >> 16) & 1u)) >> 16;
    ub = (ub + 0x7FFFu + ((ub >> 16) & 1u)) & 0xFFFF0000u;
    return ua | ub;
}
__device__ __forceinline__ unsigned short f2bf1(float a) {
    unsigned u = __float_as_uint(a);
    return (unsigned short)((u + 0x7FFFu + ((u >> 16) & 1u)) >> 16);
}
#define BF_LO(u) __uint_as_float((u) << 16)
#define BF_HI(u) __uint_as_float((u) & 0xFFFF0000u)

// ---- prep: W1t/W2t bf16 [ch][k] + zero bcursor (replaces memset dispatch) ----
__global__ __launch_bounds__(256) void k_prep(const float* __restrict__ w1,
                                              const float* __restrict__ w2,
                                              unsigned short* __restrict__ w1t,
                                              unsigned short* __restrict__ w2t,
                                              int* __restrict__ bcursor) {
    int t = blockIdx.x * 256 + threadIdx.x;      // 2048 threads
    if (t < NBUCK) bcursor[t] = 0;
    for (int i = t; i < 64 * FIN; i += 2048) {   // W1t[ch*128+k] = w1[k][ch]
        int ch = i >> 7, k = i & 127;
        w1t[i] = f2bf1(w1[k * 64 + ch]);
    }
    for (int i = t; i < 64 * 64; i += 2048) {    // W2t[ch*64+k] = w2[k][ch]
        int ch = i >> 6, k = i & 63;
        w2t[i] = f2bf1(w2[k * 64 + ch]);
    }
}

// ---- fused: edge scatter (blocks < nsc) + GEMM1 (blocks >= nsc) ----
__global__ __launch_bounds__(256) void k_scatter_mfma1(const int* __restrict__ src,
                                                       const int* __restrict__ dst,
                                                       int* __restrict__ bcursor,
                                                       int* __restrict__ pairs, int e,
                                                       const float4* __restrict__ x4,
                                                       const unsigned short* __restrict__ w1t,
                                                       uint2* __restrict__ hsb,
                                                       int n, int nsc) {
    __shared__ int sbuf[4352];            // 17408 B: sW (GEMM) / h,base,cur (scatter)
    int tid = threadIdx.x;
    if ((int)blockIdx.x < nsc) {
        int* h      = sbuf;
        int* base_s = sbuf + NBUCK;
        int* cur    = sbuf + 2 * NBUCK;
        int dloc[EPB / 256];
        for (int i = tid; i < NBUCK; i += 256) { h[i] = 0; cur[i] = 0; }
        __syncthreads();
        int start = blockIdx.x * EPB;
#pragma unroll
        for (int i = 0; i < EPB / 256; i++) {
            int idx = start + tid + i * 256;
            int d = (idx < e) ? dst[idx] : -1;
            dloc[i] = d;
            if (d >= 0) atomicAdd(&h[d >> 8], 1);
        }
        __syncthreads();
        for (int i = tid; i < NBUCK; i += 256)
            if (h[i] > 0) base_s[i] = atomicAdd(&bcursor[i], h[i]);
        __syncthreads();
#pragma unroll
        for (int i = 0; i < EPB / 256; i++) {
            int idx = start + tid + i * 256;
            int d = dloc[i];
            if (d >= 0) {
                int b = d >> 8;
                int pos = base_s[b] + atomicAdd(&cur[b], 1);
                if (pos < CAP) pairs[b * CAP + pos] = (src[idx] << 8) | (d & 255);
            }
        }
        return;
    }
    // ---- GEMM1 path: hsb[node][ch] = bf16( sum_k x[node][k] W1[k][ch] ) ----
    unsigned short* sW = (unsigned short*)sbuf;   // W1t bf16 [ch][k], stride 136
    {
        int ch = tid >> 2, k0 = (tid & 3) * 32;   // 64B per thread, vectorized
        const uint4* g = (const uint4*)(w1t + ch * 128 + k0);
        uint4* dsd = (uint4*)(sW + ch * 136 + k0);
        uint4 a = g[0], b = g[1], c = g[2], d = g[3];
        dsd[0] = a; dsd[1] = b; dsd[2] = c; dsd[3] = d;
    }
    __syncthreads();
    int lane = tid & 63, wave = tid >> 6;
    int quad = lane >> 4, nl = lane & 15;
    const bf16x8* sW8 = (const bf16x8*)sW;
    int node0g = (blockIdx.x - nsc) * 128;
#pragma unroll
    for (int hf = 0; hf < 2; hf++) {
        int node = node0g + hf * 64 + wave * 16 + nl;
        int ic = min(node, n - 1);
        const float4* px = x4 + (size_t)ic * 32 + quad * 2;
        bf16x8 bfr[4];
#pragma unroll
        for (int kc = 0; kc < 4; kc++) {
            float4 p = px[kc * 8];
            float4 q = px[kc * 8 + 1];
            union { unsigned u[4]; bf16x8 v; } t;
            t.u[0] = f2bf_pair(p.x, p.y); t.u[1] = f2bf_pair(p.z, p.w);
            t.u[2] = f2bf_pair(q.x, q.y); t.u[3] = f2bf_pair(q.z, q.w);
            bfr[kc] = t.v;
        }
        f32x4 a0 = {0.f, 0.f, 0.f, 0.f}, a1 = a0, a2 = a0, a3 = a0;
#pragma unroll
        for (int kc = 0; kc < 4; kc++) {
            int ko = kc * 4 + quad;
            bf16x8 w0  = sW8[(nl +  0) * 17 + ko];
            bf16x8 w1f = sW8[(nl + 16) * 17 + ko];
            bf16x8 w2f = sW8[(nl + 32) * 17 + ko];
            bf16x8 w3f = sW8[(nl + 48) * 17 + ko];
            a0 = __builtin_amdgcn_mfma_f32_16x16x32_bf16(w0,  bfr[kc], a0, 0, 0, 0);
            a1 = __builtin_amdgcn_mfma_f32_16x16x32_bf16(w1f, bfr[kc], a1, 0, 0, 0);
            a2 = __builtin_amdgcn_mfma_f32_16x16x32_bf16(w2f, bfr[kc], a2, 0, 0, 0);
            a3 = __builtin_amdgcn_mfma_f32_16x16x32_bf16(w3f, bfr[kc], a3, 0, 0, 0);
        }
        if (node < n) {
            uint2* o = hsb + (size_t)node * 16 + quad;
            o[0]  = make_uint2(f2bf_pair(a0.x, a0.y), f2bf_pair(a0.z, a0.w));
            o[4]  = make_uint2(f2bf_pair(a1.x, a1.y), f2bf_pair(a1.z, a1.w));
            o[8]  = make_uint2(f2bf_pair(a2.x, a2.y), f2bf_pair(a2.z, a2.w));
            o[12] = make_uint2(f2bf_pair(a3.x, a3.y), f2bf_pair(a3.z, a3.w));
        }
    }
}

// ---- per-bucket exact CSR + rowinfo{start,deg} + dinv (256 nodes/bucket) ----
__global__ __launch_bounds__(256) void k_csr_bucket(const int* __restrict__ pairs,
                                                    const int* __restrict__ bcursor,
                                                    int2* __restrict__ rowinfo,
                                                    float* __restrict__ dinv,
                                                    int* __restrict__ csr_src, int n) {
    __shared__ int cnt[256];
    __shared__ int off[256];
    __shared__ int ws[256];
    int tid = threadIdx.x;
    int b = blockIdx.x;
    int node0 = b << 8;
    cnt[tid] = 0;
    __syncthreads();
    int s0 = b * CAP;
    int s1 = s0 + min(bcursor[b], CAP);
    for (int i = s0 + tid; i < s1; i += 256) atomicAdd(&cnt[pairs[i] & 255], 1);
    __syncthreads();
    int c = cnt[tid];
    ws[tid] = c;
    __syncthreads();
    for (int o = 1; o < 256; o <<= 1) {
        int x = 0;
        if (tid >= o) x = ws[tid - o];
        __syncthreads();
        ws[tid] += x;
        __syncthreads();
    }
    int excl = ws[tid] - c;
    off[tid] = excl;
    int node = node0 + tid;
    if (node < n) {
        rowinfo[node] = make_int2(s0 + excl, c);
        dinv[node] = rsqrtf((float)c + 1.0f);
    }
    cnt[tid] = 0;
    __syncthreads();
    for (int i = s0 + tid; i < s1; i += 256) {
        int p = pairs[i];
        int l = p & 255;
        int pos = s0 + off[l] + atomicAdd(&cnt[l], 1);
        csr_src[pos] = p >> 8;
    }
}

// agg layer1 + finalize + W2 GEMM fused. Block = 32 nodes, 8 lanes/node.
// Each lane owns 8 channels (one uint4 group) of its node for ALL edges ->
// pure register accumulate, no shuffles. 4 independent gathers in flight.
__global__ __launch_bounds__(256) void k_agg1_gemm2(const int2* __restrict__ rowinfo,
                                                    const int* __restrict__ csr_src,
                                                    const uint4* __restrict__ hsb4,  // hsb1
                                                    const float* __restrict__ dinv,
                                                    const float4* __restrict__ b1_4,
                                                    const unsigned short* __restrict__ w2t,
                                                    uint2* __restrict__ hsb2, int n) {
    __shared__ unsigned short sW[64 * 72];    // W2t bf16 [ch][k], stride 72
    __shared__ float sV[32 * 68];             // v fp32 [node][k], stride 68
    int tid = threadIdx.x;
    {
        int ch = tid >> 1, k0 = (tid & 1) * 32;   // 64B per thread, vectorized
        const uint4* g = (const uint4*)(w2t + ch * 64 + k0);
        uint4* dsd = (uint4*)(sW + ch * 72 + k0);
        uint4 a = g[0], b = g[1], c = g[2], d = g[3];
        dsd[0] = a; dsd[1] = b; dsd[2] = c; dsd[3] = d;
    }
    int node0 = blockIdx.x * 32;
    int nloc = tid >> 3;                      // 0..31
    int cq = tid & 7;
    int node = node0 + nloc;
    float4 accA = make_float4(0.f, 0.f, 0.f, 0.f), accB = accA;
    float sd = 0.f;
    if (node < n) {
        int2 rpd = rowinfo[node];
        int start = rpd.x, deg = rpd.y;
        int end = start + deg;
        sd = dinv[node];
        int nr = (deg + 3) >> 2;
        for (int r = 0; r < nr; r++) {
            int base = start + (r << 2);
            int e0 = base, e1 = base + 1, e2 = base + 2, e3 = base + 3;
            int s0 = csr_src[min(e0, end - 1)];
            int s1 = csr_src[min(e1, end - 1)];
            int s2 = csr_src[min(e2, end - 1)];
            int s3 = csr_src[min(e3, end - 1)];
            float m0 = (e0 < end) ? dinv[s0] : 0.f;
            float m1 = (e1 < end) ? dinv[s1] : 0.f;
            float m2 = (e2 < end) ? dinv[s2] : 0.f;
            float m3 = (e3 < end) ? dinv[s3] : 0.f;
            uint4 g0 = hsb4[(size_t)s0 * 8 + cq];
            uint4 g1 = hsb4[(size_t)s1 * 8 + cq];
            uint4 g2 = hsb4[(size_t)s2 * 8 + cq];
            uint4 g3 = hsb4[(size_t)s3 * 8 + cq];
            accA.x += m0 * BF_LO(g0.x) + m1 * BF_LO(g1.x) + m2 * BF_LO(g2.x) + m3 * BF_LO(g3.x);
            accA.y += m0 * BF_HI(g0.x) + m1 * BF_HI(g1.x) + m2 * BF_HI(g2.x) + m3 * BF_HI(g3.x);
            accA.z += m0 * BF_LO(g0.y) + m1 * BF_LO(g1.y) + m2 * BF_LO(g2.y) + m3 * BF_LO(g3.y);
            accA.w += m0 * BF_HI(g0.y) + m1 * BF_HI(g1.y) + m2 * BF_HI(g2.y) + m3 * BF_HI(g3.y);
            accB.x += m0 * BF_LO(g0.z) + m1 * BF_LO(g1.z) + m2 * BF_LO(g2.z) + m3 * BF_LO(g3.z);
            accB.y += m0 * BF_HI(g0.z) + m1 * BF_HI(g1.z) + m2 * BF_HI(g2.z) + m3 * BF_HI(g3.z);
            accB.z += m0 * BF_LO(g0.w) + m1 * BF_LO(g1.w) + m2 * BF_LO(g2.w) + m3 * BF_LO(g3.w);
            accB.w += m0 * BF_HI(g0.w) + m1 * BF_HI(g1.w) + m2 * BF_HI(g2.w) + m3 * BF_HI(g3.w);
        }
    }
    // epilogue: v = relu(dinv*acc + dinv^2*h_self + b1) -> sV
    float4 vA = make_float4(0.f, 0.f, 0.f, 0.f), vB = vA;
    if (node < n) {
        uint4 gs = hsb4[(size_t)node * 8 + cq];
        float sq = sd * sd;
        float4 bA = b1_4[cq * 2], bB = b1_4[cq * 2 + 1];
        vA.x = fmaxf(sd * accA.x + sq * BF_LO(gs.x) + bA.x, 0.f);
        vA.y = fmaxf(sd * accA.y + sq * BF_HI(gs.x) + bA.y, 0.f);
        vA.z = fmaxf(sd * accA.z + sq * BF_LO(gs.y) + bA.z, 0.f);
        vA.w = fmaxf(sd * accA.w + sq * BF_HI(gs.y) + bA.w, 0.f);
        vB.x = fmaxf(sd * accB.x + sq * BF_LO(gs.z) + bB.x, 0.f);
        vB.y = fmaxf(sd * accB.y + sq * BF_HI(gs.z) + bB.y, 0.f);
        vB.z = fmaxf(sd * accB.z + sq * BF_LO(gs.w) + bB.z, 0.f);
        vB.w = fmaxf(sd * accB.w + sq * BF_HI(gs.w) + bB.w, 0.f);
    }
    float* vb = sV + nloc * 68 + cq * 8;
    *(float4*)vb = vA;
    *(float4*)(vb + 4) = vB;
    __syncthreads();
    // Phase B: wave w -> output channels [w*16, w*16+16) for 2 node-tiles.
    int lane = tid & 63, wave = tid >> 6;
    int quad = lane >> 4, nl = lane & 15;
    const bf16x8* sW8 = (const bf16x8*)sW;
#pragma unroll
    for (int tt = 0; tt < 2; tt++) {
        f32x4 acc = {0.f, 0.f, 0.f, 0.f};
#pragma unroll
        for (int kc = 0; kc < 2; kc++) {
            const float* vr = sV + (tt * 16 + nl) * 68 + kc * 32 + quad * 8;
            float4 p = *(const float4*)vr;
            float4 q = *(const float4*)(vr + 4);
            union { unsigned u[4]; bf16x8 v; } t;
            t.u[0] = f2bf_pair(p.x, p.y); t.u[1] = f2bf_pair(p.z, p.w);
            t.u[2] = f2bf_pair(q.x, q.y); t.u[3] = f2bf_pair(q.z, q.w);
            bf16x8 a = sW8[(wave * 16 + nl) * 9 + kc * 4 + quad];
            acc = __builtin_amdgcn_mfma_f32_16x16x32_bf16(a, t.v, acc, 0, 0, 0);
        }
        int onode = node0 + tt * 16 + nl;
        if (onode < n) {
            float s = dinv[onode];
            hsb2[(size_t)onode * 16 + wave * 4 + quad] =
                make_uint2(f2bf_pair(acc.x * s, acc.y * s), f2bf_pair(acc.z * s, acc.w * s));
        }
    }
}

// agg layer2 + head fused: 8 lanes/node, 4 edges/round, register accumulate;
// epilogue relu(dinv*(acc+self)+b2).wc+bc  (hsb2 has dinv folded -> m in {0,1})
__global__ __launch_bounds__(256) void k_agg2_head(const int2* __restrict__ rowinfo,
                                                   const int* __restrict__ csr_src,
                                                   const uint4* __restrict__ hsb4,  // hsb2
                                                   const float* __restrict__ dinv,
                                                   const float4* __restrict__ b2_4,
                                                   const float4* __restrict__ wc_4,
                                                   const float* __restrict__ bc,
                                                   float* __restrict__ out, int n) {
    int tid = threadIdx.x;
    int cq = tid & 7;
    int node = (blockIdx.x * 256 + tid) >> 3;
    if (node >= n) return;
    int2 rpd = rowinfo[node];
    int start = rpd.x, deg = rpd.y;
    int end = start + deg;
    float4 accA = make_float4(0.f, 0.f, 0.f, 0.f), accB = accA;
    int nr = (deg + 3) >> 2;
    for (int r = 0; r < nr; r++) {
        int base = start + (r << 2);
        int e0 = base, e1 = base + 1, e2 = base + 2, e3 = base + 3;
        int s0 = csr_src[min(e0, end - 1)];
        int s1 = csr_src[min(e1, end - 1)];
        int s2 = csr_src[min(e2, end - 1)];
        int s3 = csr_src[min(e3, end - 1)];
        float m0 = (e0 < end) ? 1.f : 0.f;
        float m1 = (e1 < end) ? 1.f : 0.f;
        float m2 = (e2 < end) ? 1.f : 0.f;
        float m3 = (e3 < end) ? 1.f : 0.f;
        uint4 g0 = hsb4[(size_t)s0 * 8 + cq];
        uint4 g1 = hsb4[(size_t)s1 * 8 + cq];
        uint4 g2 = hsb4[(size_t)s2 * 8 + cq];
        uint4 g3 = hsb4[(size_t)s3 * 8 + cq];
        accA.x += m0 * BF_LO(g0.x) + m1 * BF_LO(g1.x) + m2 * BF_LO(g2.x) + m3 * BF_LO(g3.x);
        accA.y += m0 * BF_HI(g0.x) + m1 * BF_HI(g1.x) + m2 * BF_HI(g2.x) + m3 * BF_HI(g3.x);
        accA.z += m0 * BF_LO(g0.y) + m1 * BF_LO(g1.y) + m2 * BF_LO(g2.y) + m3 * BF_LO(g3.y);
        accA.w += m0 * BF_HI(g0.y) + m1 * BF_HI(g1.y) + m2 * BF_HI(g2.y) + m3 * BF_HI(g3.y);
        accB.x += m0 * BF_LO(g0.z) + m1 * BF_LO(g1.z) + m2 * BF_LO(g2.z) + m3 * BF_LO(g3.z);
        accB.y += m0 * BF_HI(g0.z) + m1 * BF_HI(g1.z) + m2 * BF_HI(g2.z) + m3 * BF_HI(g3.z);
        accB.z += m0 * BF_LO(g0.w) + m1 * BF_LO(g1.w) + m2 * BF_LO(g2.w) + m3 * BF_LO(g3.w);
        accB.w += m0 * BF_HI(g0.w) + m1 * BF_HI(g1.w) + m2 * BF_HI(g2.w) + m3 * BF_HI(g3.w);
    }
    uint4 g = hsb4[(size_t)node * 8 + cq];
    float s = dinv[node];
    float4 bA = b2_4[cq * 2], bB = b2_4[cq * 2 + 1];
    float4 wA = wc_4[cq * 2], wB = wc_4[cq * 2 + 1];
    float t = fmaxf(s * (accA.x + BF_LO(g.x)) + bA.x, 0.f) * wA.x
            + fmaxf(s * (accA.y + BF_HI(g.x)) + bA.y, 0.f) * wA.y
            + fmaxf(s * (accA.z + BF_LO(g.y)) + bA.z, 0.f) * wA.z
            + fmaxf(s * (accA.w + BF_HI(g.y)) + bA.w, 0.f) * wA.w
            + fmaxf(s * (accB.x + BF_LO(g.z)) + bB.x, 0.f) * wB.x
            + fmaxf(s * (accB.y + BF_HI(g.z)) + bB.y, 0.f) * wB.y
            + fmaxf(s * (accB.z + BF_LO(g.w)) + bB.z, 0.f) * wB.z
            + fmaxf(s * (accB.w + BF_HI(g.w)) + bB.w, 0.f) * wB.w;
    t += __shfl_xor(t, 1);
    t += __shfl_xor(t, 2);
    t += __shfl_xor(t, 4);
    if (cq == 0) out[node] = t + bc[0];
}

extern "C" void kernel_launch(void* const* d_in, const int* in_sizes, int n_in,
                              void* d_out, int out_size, void* d_ws, size_t ws_size,
                              hipStream_t stream) {
    const float* x  = (const float*)d_in[0];
    const int*   ei = (const int*)d_in[1];
    const float* W1 = (const float*)d_in[2];
    const float* b1 = (const float*)d_in[3];
    const float* W2 = (const float*)d_in[4];
    const float* b2 = (const float*)d_in[5];
    const float* Wc = (const float*)d_in[6];
    const float* bc = (const float*)d_in[7];
    int n = in_sizes[0] / FIN;      // 100000
    int e = in_sizes[1] / 2;        // 1600000
    const int* srcv = ei;
    const int* dstv = ei + e;

    char* ws = (char*)d_ws;
    float* dinv    = (float*)(ws + 0);                       // 400 KB
    int2*  rowinfo = (int2*)(ws + (512u << 10));             // 800 KB
    int*   csr_src = (int*)(ws + 1536u * 1024);              // 7.21 MB (391*4608*4)
    int*   bcursor = (int*)(ws + 8800u * 1024);              // 1564 B
    unsigned short* w1t = (unsigned short*)(ws + 8816u * 1024);  // 16 KB bf16 [64][128]
    unsigned short* w2t = (unsigned short*)(ws + 8836u * 1024);  // 8 KB bf16 [64][64]
    uint2* hsb1    = (uint2*)(ws + (9u << 20));              // 12.8 MB bf16 [N,64]
    uint2* hsb2    = (uint2*)(ws + (22u << 20));             // 12.8 MB bf16 [N,64]
    int*   pairs   = (int*)hsb2;                             // 7.21 MB transient (dead before hsb2 written)

    int nb_sc   = (e + EPB - 1) / EPB;     // 391
    int nb_rows = (n + 127) / 128;         // 782 (128 nodes per GEMM block)
    int nb_agg  = (n + 31) / 32;           // 3125 (32 nodes per agg block)

    // prep: W transposes + bcursor zero (replaces memset dispatch)
    k_prep<<<8, 256, 0, stream>>>(W1, W2, w1t, w2t, bcursor);
    // fused: edge-bucket scatter (391 blocks) || layer-1 GEMM (782 blocks)
    k_scatter_mfma1<<<nb_sc + nb_rows, 256, 0, stream>>>(srcv, dstv, bcursor, pairs, e,
                                                         (const float4*)x, w1t, hsb1,
                                                         n, nb_sc);
    k_csr_bucket<<<NBUCK, 256, 0, stream>>>(pairs, bcursor, rowinfo, dinv, csr_src, n);
    // layer-1 agg (dinv[src] weights) + finalize + layer-2 GEMM fused
    k_agg1_gemm2<<<nb_agg, 256, 0, stream>>>(rowinfo, csr_src, (const uint4*)hsb1,
                                             dinv, (const float4*)b1, w2t, hsb2, n);
    // layer-2 agg + head
    k_agg2_head<<<nb_agg, 256, 0, stream>>>(rowinfo, csr_src, (const uint4*)hsb2,
                                            dinv, (const float4*)b2, (const float4*)Wc,
                                            bc, (float*)d_out, n);
}